// Round 12
// baseline (215.883 us; speedup 1.0000x reference)
//
#include <hip/hip_runtime.h>
#include <cmath>

#define TAPE_SZ 100000
#define N_SZ    50000
#define F_SZ    32
#define B_SZ    128
#define NCHUNK  8       // b-chunks (one per XCD under %8 round-robin)
#define CB      16      // b's per chunk; chunk = TAPE_SZ*CB*2B = 3.2 MB < 4 MB L2
#define NB      128     // n's per gather block
#define NTILE   391     // ceil(50000/128)
#define NGBLK   (NTILE * NCHUNK)
#define NTAIL   512
#define TAIL_F4 1600000 // 128 b * 12500 float4 tail elements

// Manual round-to-nearest-even f32 -> bf16 bits.
static __device__ __forceinline__ unsigned short f32_to_bf16(float f) {
    unsigned int u = __float_as_uint(f);
    u = (u + 0x7fffu + ((u >> 16) & 1u)) >> 16;
    return (unsigned short)u;
}

// ---------------------------------------------------------------------------
// Kernel A: tape (B x TAPE f32) -> tapeT chunked [NCHUNK][TAPE][CB] bf16.
// float4 global loads, 16B chunk-contiguous stores (R5-proven structure).
// ---------------------------------------------------------------------------
__global__ __launch_bounds__(256) void transpose_tape(const float* __restrict__ in,
                                                      unsigned short* __restrict__ outT) {
    __shared__ float tile[32 * 133];
    const int x0  = blockIdx.x * 32;
    const int tid = threadIdx.x;
    {
        const int xq = tid & 7;
        const int b0 = tid >> 3;
        #pragma unroll
        for (int it = 0; it < 4; ++it) {
            const int b = b0 + it * 32;
            const float4 v = *(const float4*)(in + (size_t)b * TAPE_SZ + x0 + xq * 4);
            tile[(xq * 4 + 0) * 133 + b] = v.x;
            tile[(xq * 4 + 1) * 133 + b] = v.y;
            tile[(xq * 4 + 2) * 133 + b] = v.z;
            tile[(xq * 4 + 3) * 133 + b] = v.w;
        }
    }
    __syncthreads();
    {
        const int s  = tid & 63;
        const int w  = tid >> 6;
        const int h  = s & 1;
        const int xr = s >> 1;
        #pragma unroll
        for (int j = 0; j < 2; ++j) {
            const int c = w + 4 * j;
            const float* src = &tile[xr * 133 + c * CB + h * 8];
            union { unsigned short u[8]; uint4 q; } pk;
            #pragma unroll
            for (int k = 0; k < 8; ++k) pk.u[k] = f32_to_bf16(src[k]);
            *(uint4*)(outT + ((size_t)c * TAPE_SZ + x0 + xr) * CB + h * 8) = pk.q;
        }
    }
}

// ---------------------------------------------------------------------------
// Kernel B: ZERO-LDS chunked gather-matmul + fused tail copy.
// Blocks [0, NGBLK): gather. chunk = blockIdx & 7 (XCD L2 affinity; R5 showed
// FETCH 179->82 MB). No __shared__ at all: idx/w read straight from global
// (oct-pair duplicates hit L1); occupancy is VGPR-bound only -> ~7 blocks/CU,
// ~28 waves/CU, ~220 outstanding gathers/CU. This arbitrates miss-BW vs
// address-rate ceiling models.
// ---------------------------------------------------------------------------
__global__ __launch_bounds__(256) void gather_mm(const unsigned short* __restrict__ tapeT,
                                                 const float* __restrict__ weights,
                                                 const float* __restrict__ bias,
                                                 const int*   __restrict__ in_idx,
                                                 const int*   __restrict__ out_idx,
                                                 const int*   __restrict__ act_type,
                                                 const float* __restrict__ tape,
                                                 float* __restrict__ out) {
    const int tid = threadIdx.x;

    if (blockIdx.x >= NGBLK) {
        // ---- tail copy: columns [N_SZ, TAPE_SZ) survive into out ----
        const float4* src = (const float4*)tape;
        float4*       dst = (float4*)out;
        const int stride = NTAIL * 256;
        for (int i = (blockIdx.x - NGBLK) * 256 + tid; i < TAIL_F4; i += stride) {
            const int b = i / 12500;
            const int j = i - b * 12500;
            const int off = b * (TAPE_SZ / 4) + (N_SZ / 4) + j;
            dst[off] = src[off];
        }
        return;
    }

    const int c   = blockIdx.x & 7;
    const int n0  = (blockIdx.x >> 3) * NB;
    const int oct = tid & 1;
    const int nl  = tid >> 1;
    const int n   = n0 + nl;
    if (n >= N_SZ) return;

    const uint4*  gi = (const uint4*)(in_idx  + (size_t)n * 32);
    const float4* gw = (const float4*)(weights + (size_t)n * 32);
    const unsigned short* base = tapeT + (size_t)c * TAPE_SZ * CB + oct * 8;

    float a0 = 0.f, a1 = 0.f, a2 = 0.f, a3 = 0.f, a4 = 0.f, a5 = 0.f, a6 = 0.f, a7 = 0.f;

    #pragma unroll
    for (int fo = 0; fo < 4; ++fo) {           // 4 batches x 8 f
        const uint4  ia = gi[fo * 2], ib = gi[fo * 2 + 1];
        const float4 wa = gw[fo * 2], wb = gw[fo * 2 + 1];
        uint4 q8[8];
        q8[0] = *(const uint4*)(base + (size_t)ia.x * CB);
        q8[1] = *(const uint4*)(base + (size_t)ia.y * CB);
        q8[2] = *(const uint4*)(base + (size_t)ia.z * CB);
        q8[3] = *(const uint4*)(base + (size_t)ia.w * CB);
        q8[4] = *(const uint4*)(base + (size_t)ib.x * CB);
        q8[5] = *(const uint4*)(base + (size_t)ib.y * CB);
        q8[6] = *(const uint4*)(base + (size_t)ib.z * CB);
        q8[7] = *(const uint4*)(base + (size_t)ib.w * CB);
        const float w8[8] = { wa.x, wa.y, wa.z, wa.w, wb.x, wb.y, wb.z, wb.w };
        #pragma unroll
        for (int j = 0; j < 8; ++j) {
            const float w = w8[j];
            a0 = fmaf(__uint_as_float(q8[j].x << 16),         w, a0);
            a1 = fmaf(__uint_as_float(q8[j].x & 0xffff0000u), w, a1);
            a2 = fmaf(__uint_as_float(q8[j].y << 16),         w, a2);
            a3 = fmaf(__uint_as_float(q8[j].y & 0xffff0000u), w, a3);
            a4 = fmaf(__uint_as_float(q8[j].z << 16),         w, a4);
            a5 = fmaf(__uint_as_float(q8[j].z & 0xffff0000u), w, a5);
            a6 = fmaf(__uint_as_float(q8[j].w << 16),         w, a6);
            a7 = fmaf(__uint_as_float(q8[j].w & 0xffff0000u), w, a7);
        }
    }

    const float bz = bias[n];
    a0 += bz; a1 += bz; a2 += bz; a3 += bz; a4 += bz; a5 += bz; a6 += bz; a7 += bz;
    if (act_type[n] == 0) {
        a0 = fmaxf(a0, 0.f); a1 = fmaxf(a1, 0.f); a2 = fmaxf(a2, 0.f); a3 = fmaxf(a3, 0.f);
        a4 = fmaxf(a4, 0.f); a5 = fmaxf(a5, 0.f); a6 = fmaxf(a6, 0.f); a7 = fmaxf(a7, 0.f);
    } else {
        a0 = tanhf(a0); a1 = tanhf(a1); a2 = tanhf(a2); a3 = tanhf(a3);
        a4 = tanhf(a4); a5 = tanhf(a5); a6 = tanhf(a6); a7 = tanhf(a7);
    }
    const int oc = out_idx[n];
    const int bb = c * CB + oct * 8;
    out[(size_t)(bb + 0) * TAPE_SZ + oc] = a0;
    out[(size_t)(bb + 1) * TAPE_SZ + oc] = a1;
    out[(size_t)(bb + 2) * TAPE_SZ + oc] = a2;
    out[(size_t)(bb + 3) * TAPE_SZ + oc] = a3;
    out[(size_t)(bb + 4) * TAPE_SZ + oc] = a4;
    out[(size_t)(bb + 5) * TAPE_SZ + oc] = a5;
    out[(size_t)(bb + 6) * TAPE_SZ + oc] = a6;
    out[(size_t)(bb + 7) * TAPE_SZ + oc] = a7;
}

// ---------------------------------------------------------------------------
// Fallback (workspace too small): direct uncoalesced gather. Correct, slow.
// ---------------------------------------------------------------------------
__global__ __launch_bounds__(128) void gather_fallback(const float* __restrict__ tape,
                                                       const float* __restrict__ weights,
                                                       const float* __restrict__ bias,
                                                       const int*   __restrict__ in_idx,
                                                       const int*   __restrict__ out_idx,
                                                       const int*   __restrict__ act_type,
                                                       float* __restrict__ out) {
    const int n = blockIdx.x;
    const int b = threadIdx.x;
    float acc = 0.f;
    for (int f = 0; f < F_SZ; ++f) {
        acc += tape[(size_t)b * TAPE_SZ + in_idx[(size_t)n * F_SZ + f]] *
               weights[(size_t)n * F_SZ + f];
    }
    acc += bias[n];
    acc = (act_type[n] == 0) ? fmaxf(acc, 0.f) : tanhf(acc);
    out[(size_t)b * TAPE_SZ + out_idx[n]] = acc;
}

__global__ __launch_bounds__(256) void copy_tail_fb(const float* __restrict__ tape,
                                                    float* __restrict__ out) {
    const int n4 = (TAPE_SZ - N_SZ) / 4;
    int i = blockIdx.x * blockDim.x + threadIdx.x;
    int b = blockIdx.y;
    if (i < n4) {
        const float4* src = (const float4*)(tape + (size_t)b * TAPE_SZ + N_SZ);
        float4*       dst = (float4*)(out  + (size_t)b * TAPE_SZ + N_SZ);
        dst[i] = src[i];
    }
}

extern "C" void kernel_launch(void* const* d_in, const int* in_sizes, int n_in,
                              void* d_out, int out_size, void* d_ws, size_t ws_size,
                              hipStream_t stream) {
    const float* tape    = (const float*)d_in[0];
    const float* weights = (const float*)d_in[1];
    const float* bias    = (const float*)d_in[2];
    const int*   in_idx  = (const int*)d_in[3];
    const int*   out_idx = (const int*)d_in[4];
    const int*   act     = (const int*)d_in[5];
    float*       out     = (float*)d_out;

    const size_t need = (size_t)NCHUNK * TAPE_SZ * CB * sizeof(unsigned short);
    if (ws_size >= need) {
        unsigned short* tapeT = (unsigned short*)d_ws;
        transpose_tape<<<dim3(TAPE_SZ / 32), dim3(256), 0, stream>>>(tape, tapeT);
        gather_mm<<<dim3(NGBLK + NTAIL), dim3(256), 0, stream>>>(
            tapeT, weights, bias, in_idx, out_idx, act, tape, out);
    } else {
        copy_tail_fb<<<dim3(((TAPE_SZ - N_SZ) / 4 + 255) / 256, B_SZ), 256, 0, stream>>>(tape, out);
        gather_fallback<<<dim3(N_SZ), 128, 0, stream>>>(
            tape, weights, bias, in_idx, out_idx, act, out);
    }
}